// Round 6
// baseline (669.295 us; speedup 1.0000x reference)
//
#include <hip/hip_runtime.h>

#define NUM_JOINTS 24

typedef float fvec4 __attribute__((ext_vector_type(4)));

// Ancestor path (root -> joint) for each joint, padded with -1.
__device__ __constant__ int d_chain[NUM_JOINTS][9] = {
    {0,-1,-1,-1,-1,-1,-1,-1,-1},
    {0,1,-1,-1,-1,-1,-1,-1,-1},
    {0,2,-1,-1,-1,-1,-1,-1,-1},
    {0,3,-1,-1,-1,-1,-1,-1,-1},
    {0,1,4,-1,-1,-1,-1,-1,-1},
    {0,2,5,-1,-1,-1,-1,-1,-1},
    {0,3,6,-1,-1,-1,-1,-1,-1},
    {0,1,4,7,-1,-1,-1,-1,-1},
    {0,2,5,8,-1,-1,-1,-1,-1},
    {0,3,6,9,-1,-1,-1,-1,-1},
    {0,1,4,7,10,-1,-1,-1,-1},
    {0,2,5,8,11,-1,-1,-1,-1},
    {0,3,6,9,12,-1,-1,-1,-1},
    {0,3,6,9,13,-1,-1,-1,-1},
    {0,3,6,9,14,-1,-1,-1,-1},
    {0,3,6,9,12,15,-1,-1,-1},
    {0,3,6,9,13,16,-1,-1,-1},
    {0,3,6,9,14,17,-1,-1,-1},
    {0,3,6,9,13,16,18,-1,-1},
    {0,3,6,9,14,17,19,-1,-1},
    {0,3,6,9,13,16,18,20,-1},
    {0,3,6,9,14,17,19,21,-1},
    {0,3,6,9,13,16,18,20,22},
    {0,3,6,9,14,17,19,21,23},
};

// a*s + c  (vector * scalar + vector)
__device__ __forceinline__ fvec4 fma4s(fvec4 a, float s, fvec4 c) {
    fvec4 r;
    r.x = fmaf(a.x, s, c.x); r.y = fmaf(a.y, s, c.y);
    r.z = fmaf(a.z, s, c.z); r.w = fmaf(a.w, s, c.w);
    return r;
}
// a*b + c  (elementwise)
__device__ __forceinline__ fvec4 fma4v(fvec4 a, fvec4 b, fvec4 c) {
    fvec4 r;
    r.x = fmaf(a.x, b.x, c.x); r.y = fmaf(a.y, b.y, c.y);
    r.z = fmaf(a.z, b.z, c.z); r.w = fmaf(a.w, b.w, c.w);
    return r;
}
// a*s (vector * scalar)
__device__ __forceinline__ fvec4 mul4s(fvec4 a, float s) {
    fvec4 r; r.x = a.x * s; r.y = a.y * s; r.z = a.z * s; r.w = a.w * s;
    return r;
}

// Fused chain + skinning, 4 verts/thread (1 fvec4 stream), dot-product
// formulation out_i += w_k * (G_k @ n)_i. Register budget: 3 out accums (12)
// + 3 normals (12) + w (4) + transients -> targets <=64 VGPR via
// __launch_bounds__(256,8) for 32 waves/CU (2x the R5 kernel's 16).
// R staged in LDS padded [24][12] -> ds_read_b128 broadcasts, 0 conflicts.
// Non-temporal global access: 192 MB streamed >> 32 MB L2.
__global__ __launch_bounds__(256, 8) void skin_fused_kernel(
    const float* __restrict__ normals,
    const float* __restrict__ pose,
    const float* __restrict__ weights,
    float* __restrict__ out,
    int N) {
    __shared__ float L[NUM_JOINTS][9];
    __shared__ fvec4 Rl[NUM_JOINTS][3];  // global rots, rows padded 9->12 floats

    const int b = blockIdx.y;
    const int tid = threadIdx.x;

    // --- chain computation (lanes 0..23 of wave 0) ---
    if (tid < NUM_JOINTS) {
        float x = pose[b * 72 + tid * 3 + 0];
        float y = pose[b * 72 + tid * 3 + 1];
        float z = pose[b * 72 + tid * 3 + 2];
        // reference: angle = norm(axisang + 1e-8); axis = axisang / angle
        float ax = x + 1e-8f, ay = y + 1e-8f, az = z + 1e-8f;
        float angle = sqrtf(ax * ax + ay * ay + az * az);
        float inv = 1.0f / angle;
        float ux = x * inv, uy = y * inv, uz = z * inv;
        float c = __cosf(angle), s = __sinf(angle), t = 1.0f - c;
        L[tid][0] = c + t * ux * ux;
        L[tid][1] = t * ux * uy - s * uz;
        L[tid][2] = t * ux * uz + s * uy;
        L[tid][3] = t * uy * ux + s * uz;
        L[tid][4] = c + t * uy * uy;
        L[tid][5] = t * uy * uz - s * ux;
        L[tid][6] = t * uz * ux - s * uy;
        L[tid][7] = t * uz * uy + s * ux;
        L[tid][8] = c + t * uz * uz;
    }
    __syncthreads();

    if (tid < NUM_JOINTS) {
        // each lane composes its own ancestor path: G = L[c0] @ L[c1] @ ...
        float G[9];
        int j0 = d_chain[tid][0];  // always 0
        #pragma unroll
        for (int e = 0; e < 9; e++) G[e] = L[j0][e];
        #pragma unroll
        for (int d = 1; d < 9; d++) {
            int j = d_chain[tid][d];
            if (j >= 0) {
                float T[9];
                #pragma unroll
                for (int r = 0; r < 3; r++) {
                    #pragma unroll
                    for (int cc = 0; cc < 3; cc++) {
                        T[r * 3 + cc] = G[r * 3 + 0] * L[j][0 * 3 + cc]
                                      + G[r * 3 + 1] * L[j][1 * 3 + cc]
                                      + G[r * 3 + 2] * L[j][2 * 3 + cc];
                    }
                }
                #pragma unroll
                for (int e = 0; e < 9; e++) G[e] = T[e];
            }
        }
        float* Rf = (float*)Rl;
        #pragma unroll
        for (int e = 0; e < 9; e++) Rf[tid * 12 + e] = G[e];
    }
    __syncthreads();

    // --- skinning ---
    const int q = blockIdx.x * blockDim.x + tid;  // float4 index
    const int nf4 = N >> 2;                       // float4s per row

    const fvec4* __restrict__ Wb = (const fvec4*)(weights + (size_t)b * NUM_JOINTS * N);
    const fvec4* __restrict__ Nb = (const fvec4*)(normals + (size_t)b * 3 * N);
    fvec4* __restrict__ Ob = (fvec4*)(out + (size_t)b * 3 * N);

    if (q < nf4) {
        fvec4 nx = __builtin_nontemporal_load(&Nb[(size_t)0 * nf4 + q]);
        fvec4 ny = __builtin_nontemporal_load(&Nb[(size_t)1 * nf4 + q]);
        fvec4 nz = __builtin_nontemporal_load(&Nb[(size_t)2 * nf4 + q]);

        fvec4 o0 = (fvec4)(0.f), o1 = (fvec4)(0.f), o2 = (fvec4)(0.f);

        #pragma unroll
        for (int k = 0; k < NUM_JOINTS; k++) {
            fvec4 w = __builtin_nontemporal_load(&Wb[(size_t)k * nf4 + q]);
            fvec4 r0 = Rl[k][0];  // {M00,M01,M02,M10}
            fvec4 r1 = Rl[k][1];  // {M11,M12,M20,M21}
            fvec4 r2 = Rl[k][2];  // {M22,pad,pad,pad}
            // t_i = (G_k @ n)_i, per vertex lane
            fvec4 t0 = fma4s(nx, r0.x, fma4s(ny, r0.y, mul4s(nz, r0.z)));
            fvec4 t1 = fma4s(nx, r0.w, fma4s(ny, r1.x, mul4s(nz, r1.y)));
            fvec4 t2 = fma4s(nx, r1.z, fma4s(ny, r1.w, mul4s(nz, r2.x)));
            o0 = fma4v(w, t0, o0);
            o1 = fma4v(w, t1, o1);
            o2 = fma4v(w, t2, o2);
        }

        __builtin_nontemporal_store(o0, &Ob[(size_t)0 * nf4 + q]);
        __builtin_nontemporal_store(o1, &Ob[(size_t)1 * nf4 + q]);
        __builtin_nontemporal_store(o2, &Ob[(size_t)2 * nf4 + q]);
    } else if (q == nf4 && (N & 3) != 0) {
        // scalar tail: vertices [4*nf4, N) (not hit for N=100000)
        const float* Rf = (const float*)Rl;
        for (int n = nf4 * 4; n < N; n++) {
            float vx = normals[(size_t)b * 3 * N + 0 * N + n];
            float vy = normals[(size_t)b * 3 * N + 1 * N + n];
            float vz = normals[(size_t)b * 3 * N + 2 * N + n];
            float s0 = 0.f, s1 = 0.f, s2 = 0.f;
            for (int k = 0; k < NUM_JOINTS; k++) {
                float w = weights[(size_t)b * NUM_JOINTS * N + (size_t)k * N + n];
                float t0 = Rf[k*12+0] * vx + Rf[k*12+1] * vy + Rf[k*12+2] * vz;
                float t1 = Rf[k*12+3] * vx + Rf[k*12+4] * vy + Rf[k*12+5] * vz;
                float t2 = Rf[k*12+6] * vx + Rf[k*12+7] * vy + Rf[k*12+8] * vz;
                s0 = fmaf(w, t0, s0); s1 = fmaf(w, t1, s1); s2 = fmaf(w, t2, s2);
            }
            out[(size_t)b * 3 * N + 0 * N + n] = s0;
            out[(size_t)b * 3 * N + 1 * N + n] = s1;
            out[(size_t)b * 3 * N + 2 * N + n] = s2;
        }
    }
}

extern "C" void kernel_launch(void* const* d_in, const int* in_sizes, int n_in,
                              void* d_out, int out_size, void* d_ws, size_t ws_size,
                              hipStream_t stream) {
    const float* normals = (const float*)d_in[0];  // (B,3,N)
    const float* pose = (const float*)d_in[1];     // (B,72)
    const float* weights = (const float*)d_in[2];  // (B,24,N)
    float* out = (float*)d_out;                    // (B,3,N)

    const int B = in_sizes[1] / 72;
    const int N = in_sizes[0] / (3 * B);

    const int nf4 = N >> 2;
    const int slots = nf4 + ((N & 3) ? 1 : 0);
    const int gx = (slots + 255) / 256;
    skin_fused_kernel<<<dim3(gx, B), dim3(256), 0, stream>>>(normals, pose, weights, out, N);
}

// Round 7
// 240.253 us; speedup vs baseline: 2.7858x; 2.7858x over previous
//
#include <hip/hip_runtime.h>

#define NUM_JOINTS 24

typedef float fvec4 __attribute__((ext_vector_type(4)));

// Ancestor path (root -> joint) for each joint, padded with -1.
__device__ __constant__ int d_chain[NUM_JOINTS][9] = {
    {0,-1,-1,-1,-1,-1,-1,-1,-1},
    {0,1,-1,-1,-1,-1,-1,-1,-1},
    {0,2,-1,-1,-1,-1,-1,-1,-1},
    {0,3,-1,-1,-1,-1,-1,-1,-1},
    {0,1,4,-1,-1,-1,-1,-1,-1},
    {0,2,5,-1,-1,-1,-1,-1,-1},
    {0,3,6,-1,-1,-1,-1,-1,-1},
    {0,1,4,7,-1,-1,-1,-1,-1},
    {0,2,5,8,-1,-1,-1,-1,-1},
    {0,3,6,9,-1,-1,-1,-1,-1},
    {0,1,4,7,10,-1,-1,-1,-1},
    {0,2,5,8,11,-1,-1,-1,-1},
    {0,3,6,9,12,-1,-1,-1,-1},
    {0,3,6,9,13,-1,-1,-1,-1},
    {0,3,6,9,14,-1,-1,-1,-1},
    {0,3,6,9,12,15,-1,-1,-1},
    {0,3,6,9,13,16,-1,-1,-1},
    {0,3,6,9,14,17,-1,-1,-1},
    {0,3,6,9,13,16,18,-1,-1},
    {0,3,6,9,14,17,19,-1,-1},
    {0,3,6,9,13,16,18,20,-1},
    {0,3,6,9,14,17,19,21,-1},
    {0,3,6,9,13,16,18,20,22},
    {0,3,6,9,14,17,19,21,23},
};

// a*s + c  (vector * scalar + vector)
__device__ __forceinline__ fvec4 fma4s(fvec4 a, float s, fvec4 c) {
    fvec4 r;
    r.x = fmaf(a.x, s, c.x); r.y = fmaf(a.y, s, c.y);
    r.z = fmaf(a.z, s, c.z); r.w = fmaf(a.w, s, c.w);
    return r;
}
// a*b + c  (elementwise)
__device__ __forceinline__ fvec4 fma4v(fvec4 a, fvec4 b, fvec4 c) {
    fvec4 r;
    r.x = fmaf(a.x, b.x, c.x); r.y = fmaf(a.y, b.y, c.y);
    r.z = fmaf(a.z, b.z, c.z); r.w = fmaf(a.w, b.w, c.w);
    return r;
}
// a*s (vector * scalar)
__device__ __forceinline__ fvec4 mul4s(fvec4 a, float s) {
    fvec4 r; r.x = a.x * s; r.y = a.y * s; r.z = a.z * s; r.w = a.w * s;
    return r;
}

// Fused chain + skinning, 4 verts/thread, dot-product formulation
// out_i += w_k * (G_k @ n)_i. Live state: 3 normals + 3 accums + w + addrs
// -> ~48-64 VGPR natural allocation.
// R6 LESSON: __launch_bounds__(256,8) forced VGPR=32 -> scratch spills,
// 1.25 GB of spill traffic, 515 us. Default bounds here; let the
// allocator pick. R staged in LDS padded [24][12] -> ds_read_b128
// broadcasts, 0 conflicts. Non-temporal global access: 192 MB >> 32 MB L2.
__global__ __launch_bounds__(256) void skin_fused_kernel(
    const float* __restrict__ normals,
    const float* __restrict__ pose,
    const float* __restrict__ weights,
    float* __restrict__ out,
    int N) {
    __shared__ float L[NUM_JOINTS][9];
    __shared__ fvec4 Rl[NUM_JOINTS][3];  // global rots, rows padded 9->12 floats

    const int b = blockIdx.y;
    const int tid = threadIdx.x;

    // --- chain computation (lanes 0..23 of wave 0) ---
    if (tid < NUM_JOINTS) {
        float x = pose[b * 72 + tid * 3 + 0];
        float y = pose[b * 72 + tid * 3 + 1];
        float z = pose[b * 72 + tid * 3 + 2];
        // reference: angle = norm(axisang + 1e-8); axis = axisang / angle
        float ax = x + 1e-8f, ay = y + 1e-8f, az = z + 1e-8f;
        float angle = sqrtf(ax * ax + ay * ay + az * az);
        float inv = 1.0f / angle;
        float ux = x * inv, uy = y * inv, uz = z * inv;
        float c = __cosf(angle), s = __sinf(angle), t = 1.0f - c;
        L[tid][0] = c + t * ux * ux;
        L[tid][1] = t * ux * uy - s * uz;
        L[tid][2] = t * ux * uz + s * uy;
        L[tid][3] = t * uy * ux + s * uz;
        L[tid][4] = c + t * uy * uy;
        L[tid][5] = t * uy * uz - s * ux;
        L[tid][6] = t * uz * ux - s * uy;
        L[tid][7] = t * uz * uy + s * ux;
        L[tid][8] = c + t * uz * uz;
    }
    __syncthreads();

    if (tid < NUM_JOINTS) {
        // each lane composes its own ancestor path: G = L[c0] @ L[c1] @ ...
        float G[9];
        int j0 = d_chain[tid][0];  // always 0
        #pragma unroll
        for (int e = 0; e < 9; e++) G[e] = L[j0][e];
        #pragma unroll
        for (int d = 1; d < 9; d++) {
            int j = d_chain[tid][d];
            if (j >= 0) {
                float T[9];
                #pragma unroll
                for (int r = 0; r < 3; r++) {
                    #pragma unroll
                    for (int cc = 0; cc < 3; cc++) {
                        T[r * 3 + cc] = G[r * 3 + 0] * L[j][0 * 3 + cc]
                                      + G[r * 3 + 1] * L[j][1 * 3 + cc]
                                      + G[r * 3 + 2] * L[j][2 * 3 + cc];
                    }
                }
                #pragma unroll
                for (int e = 0; e < 9; e++) G[e] = T[e];
            }
        }
        float* Rf = (float*)Rl;
        #pragma unroll
        for (int e = 0; e < 9; e++) Rf[tid * 12 + e] = G[e];
    }
    __syncthreads();

    // --- skinning ---
    const int q = blockIdx.x * blockDim.x + tid;  // float4 index
    const int nf4 = N >> 2;                       // float4s per row

    const fvec4* __restrict__ Wb = (const fvec4*)(weights + (size_t)b * NUM_JOINTS * N);
    const fvec4* __restrict__ Nb = (const fvec4*)(normals + (size_t)b * 3 * N);
    fvec4* __restrict__ Ob = (fvec4*)(out + (size_t)b * 3 * N);

    if (q < nf4) {
        fvec4 nx = __builtin_nontemporal_load(&Nb[(size_t)0 * nf4 + q]);
        fvec4 ny = __builtin_nontemporal_load(&Nb[(size_t)1 * nf4 + q]);
        fvec4 nz = __builtin_nontemporal_load(&Nb[(size_t)2 * nf4 + q]);

        fvec4 o0 = (fvec4)(0.f), o1 = (fvec4)(0.f), o2 = (fvec4)(0.f);

        #pragma unroll
        for (int k = 0; k < NUM_JOINTS; k++) {
            fvec4 w = __builtin_nontemporal_load(&Wb[(size_t)k * nf4 + q]);
            fvec4 r0 = Rl[k][0];  // {M00,M01,M02,M10}
            fvec4 r1 = Rl[k][1];  // {M11,M12,M20,M21}
            fvec4 r2 = Rl[k][2];  // {M22,pad,pad,pad}
            // t_i = (G_k @ n)_i, per vertex lane
            fvec4 t0 = fma4s(nx, r0.x, fma4s(ny, r0.y, mul4s(nz, r0.z)));
            fvec4 t1 = fma4s(nx, r0.w, fma4s(ny, r1.x, mul4s(nz, r1.y)));
            fvec4 t2 = fma4s(nx, r1.z, fma4s(ny, r1.w, mul4s(nz, r2.x)));
            o0 = fma4v(w, t0, o0);
            o1 = fma4v(w, t1, o1);
            o2 = fma4v(w, t2, o2);
        }

        __builtin_nontemporal_store(o0, &Ob[(size_t)0 * nf4 + q]);
        __builtin_nontemporal_store(o1, &Ob[(size_t)1 * nf4 + q]);
        __builtin_nontemporal_store(o2, &Ob[(size_t)2 * nf4 + q]);
    } else if (q == nf4 && (N & 3) != 0) {
        // scalar tail: vertices [4*nf4, N) (not hit for N=100000)
        const float* Rf = (const float*)Rl;
        for (int n = nf4 * 4; n < N; n++) {
            float vx = normals[(size_t)b * 3 * N + 0 * N + n];
            float vy = normals[(size_t)b * 3 * N + 1 * N + n];
            float vz = normals[(size_t)b * 3 * N + 2 * N + n];
            float s0 = 0.f, s1 = 0.f, s2 = 0.f;
            for (int k = 0; k < NUM_JOINTS; k++) {
                float w = weights[(size_t)b * NUM_JOINTS * N + (size_t)k * N + n];
                float t0 = Rf[k*12+0] * vx + Rf[k*12+1] * vy + Rf[k*12+2] * vz;
                float t1 = Rf[k*12+3] * vx + Rf[k*12+4] * vy + Rf[k*12+5] * vz;
                float t2 = Rf[k*12+6] * vx + Rf[k*12+7] * vy + Rf[k*12+8] * vz;
                s0 = fmaf(w, t0, s0); s1 = fmaf(w, t1, s1); s2 = fmaf(w, t2, s2);
            }
            out[(size_t)b * 3 * N + 0 * N + n] = s0;
            out[(size_t)b * 3 * N + 1 * N + n] = s1;
            out[(size_t)b * 3 * N + 2 * N + n] = s2;
        }
    }
}

extern "C" void kernel_launch(void* const* d_in, const int* in_sizes, int n_in,
                              void* d_out, int out_size, void* d_ws, size_t ws_size,
                              hipStream_t stream) {
    const float* normals = (const float*)d_in[0];  // (B,3,N)
    const float* pose = (const float*)d_in[1];     // (B,72)
    const float* weights = (const float*)d_in[2];  // (B,24,N)
    float* out = (float*)d_out;                    // (B,3,N)

    const int B = in_sizes[1] / 72;
    const int N = in_sizes[0] / (3 * B);

    const int nf4 = N >> 2;
    const int slots = nf4 + ((N & 3) ? 1 : 0);
    const int gx = (slots + 255) / 256;
    skin_fused_kernel<<<dim3(gx, B), dim3(256), 0, stream>>>(normals, pose, weights, out, N);
}

// Round 8
// 223.863 us; speedup vs baseline: 2.9898x; 1.0732x over previous
//
#include <hip/hip_runtime.h>

#define NUM_JOINTS 24

typedef float fvec4 __attribute__((ext_vector_type(4)));

// Ancestor path (root -> joint) for each joint, padded with -1.
__device__ __constant__ int d_chain[NUM_JOINTS][9] = {
    {0,-1,-1,-1,-1,-1,-1,-1,-1},
    {0,1,-1,-1,-1,-1,-1,-1,-1},
    {0,2,-1,-1,-1,-1,-1,-1,-1},
    {0,3,-1,-1,-1,-1,-1,-1,-1},
    {0,1,4,-1,-1,-1,-1,-1,-1},
    {0,2,5,-1,-1,-1,-1,-1,-1},
    {0,3,6,-1,-1,-1,-1,-1,-1},
    {0,1,4,7,-1,-1,-1,-1,-1},
    {0,2,5,8,-1,-1,-1,-1,-1},
    {0,3,6,9,-1,-1,-1,-1,-1},
    {0,1,4,7,10,-1,-1,-1,-1},
    {0,2,5,8,11,-1,-1,-1,-1},
    {0,3,6,9,12,-1,-1,-1,-1},
    {0,3,6,9,13,-1,-1,-1,-1},
    {0,3,6,9,14,-1,-1,-1,-1},
    {0,3,6,9,12,15,-1,-1,-1},
    {0,3,6,9,13,16,-1,-1,-1},
    {0,3,6,9,14,17,-1,-1,-1},
    {0,3,6,9,13,16,18,-1,-1},
    {0,3,6,9,14,17,19,-1,-1},
    {0,3,6,9,13,16,18,20,-1},
    {0,3,6,9,14,17,19,21,-1},
    {0,3,6,9,13,16,18,20,22},
    {0,3,6,9,14,17,19,21,23},
};

// a*s + c  (vector * scalar + vector)
__device__ __forceinline__ fvec4 fma4s(fvec4 a, float s, fvec4 c) {
    fvec4 r;
    r.x = fmaf(a.x, s, c.x); r.y = fmaf(a.y, s, c.y);
    r.z = fmaf(a.z, s, c.z); r.w = fmaf(a.w, s, c.w);
    return r;
}
// a*b + c  (elementwise)
__device__ __forceinline__ fvec4 fma4v(fvec4 a, fvec4 b, fvec4 c) {
    fvec4 r;
    r.x = fmaf(a.x, b.x, c.x); r.y = fmaf(a.y, b.y, c.y);
    r.z = fmaf(a.z, b.z, c.z); r.w = fmaf(a.w, b.w, c.w);
    return r;
}
// a*s (vector * scalar)
__device__ __forceinline__ fvec4 mul4s(fvec4 a, float s) {
    fvec4 r; r.x = a.x * s; r.y = a.y * s; r.z = a.z * s; r.w = a.w * s;
    return r;
}

// Fused chain + skinning, 16 verts/thread as FOUR blocked float4 streams.
// Evidence trail: R5 (8v, 71us-est) beat R7 (4v, 86us-est) with identical
// arithmetic/vert -> latency-bound on per-thread MLP, not occupancy.
// Dot-product form out_i += w_k*(G_k@n)_i keeps live state at 24 fvec4
// (4 groups x (3 normals + 3 accums)) = 96 VGPR fixed; unroll-2 w-window
// (8 loads) -> ~140 VGPR, 3 waves/SIMD, NO min-waves clause (R6 spill
// lesson). Every load/store is unit-stride across the wave (64x16B=1KB).
// Non-temporal: 192 MB streamed >> 32 MB L2.
__global__ __launch_bounds__(256) void skin_fused16_kernel(
    const float* __restrict__ normals,
    const float* __restrict__ pose,
    const float* __restrict__ weights,
    float* __restrict__ out,
    int N) {
    __shared__ float L[NUM_JOINTS][9];
    __shared__ fvec4 Rl[NUM_JOINTS][3];  // global rots, rows padded 9->12 floats

    const int b = blockIdx.y;
    const int tid = threadIdx.x;

    // --- chain computation (lanes 0..23 of wave 0) ---
    if (tid < NUM_JOINTS) {
        float x = pose[b * 72 + tid * 3 + 0];
        float y = pose[b * 72 + tid * 3 + 1];
        float z = pose[b * 72 + tid * 3 + 2];
        // reference: angle = norm(axisang + 1e-8); axis = axisang / angle
        float ax = x + 1e-8f, ay = y + 1e-8f, az = z + 1e-8f;
        float angle = sqrtf(ax * ax + ay * ay + az * az);
        float inv = 1.0f / angle;
        float ux = x * inv, uy = y * inv, uz = z * inv;
        float c = __cosf(angle), s = __sinf(angle), t = 1.0f - c;
        L[tid][0] = c + t * ux * ux;
        L[tid][1] = t * ux * uy - s * uz;
        L[tid][2] = t * ux * uz + s * uy;
        L[tid][3] = t * uy * ux + s * uz;
        L[tid][4] = c + t * uy * uy;
        L[tid][5] = t * uy * uz - s * ux;
        L[tid][6] = t * uz * ux - s * uy;
        L[tid][7] = t * uz * uy + s * ux;
        L[tid][8] = c + t * uz * uz;
    }
    __syncthreads();

    if (tid < NUM_JOINTS) {
        // each lane composes its own ancestor path: G = L[c0] @ L[c1] @ ...
        float G[9];
        int j0 = d_chain[tid][0];  // always 0
        #pragma unroll
        for (int e = 0; e < 9; e++) G[e] = L[j0][e];
        #pragma unroll
        for (int d = 1; d < 9; d++) {
            int j = d_chain[tid][d];
            if (j >= 0) {
                float T[9];
                #pragma unroll
                for (int r = 0; r < 3; r++) {
                    #pragma unroll
                    for (int cc = 0; cc < 3; cc++) {
                        T[r * 3 + cc] = G[r * 3 + 0] * L[j][0 * 3 + cc]
                                      + G[r * 3 + 1] * L[j][1 * 3 + cc]
                                      + G[r * 3 + 2] * L[j][2 * 3 + cc];
                    }
                }
                #pragma unroll
                for (int e = 0; e < 9; e++) G[e] = T[e];
            }
        }
        float* Rf = (float*)Rl;
        #pragma unroll
        for (int e = 0; e < 9; e++) Rf[tid * 12 + e] = G[e];
    }
    __syncthreads();

    // --- skinning ---
    const int q = blockIdx.x * blockDim.x + tid;  // stream-0 float4 index
    const int nf4 = N >> 2;                       // float4s per row
    const int n16 = nf4 >> 2;                     // float4s per stream (4 streams)

    const fvec4* __restrict__ Wb = (const fvec4*)(weights + (size_t)b * NUM_JOINTS * N);
    const fvec4* __restrict__ Nb = (const fvec4*)(normals + (size_t)b * 3 * N);
    fvec4* __restrict__ Ob = (fvec4*)(out + (size_t)b * 3 * N);

    if (q < n16) {
        int qg[4];
        #pragma unroll
        for (int g = 0; g < 4; g++) qg[g] = q + g * n16;

        fvec4 nx[4], ny[4], nz[4], o0[4], o1[4], o2[4];
        #pragma unroll
        for (int g = 0; g < 4; g++) {
            nx[g] = __builtin_nontemporal_load(&Nb[(size_t)0 * nf4 + qg[g]]);
            ny[g] = __builtin_nontemporal_load(&Nb[(size_t)1 * nf4 + qg[g]]);
            nz[g] = __builtin_nontemporal_load(&Nb[(size_t)2 * nf4 + qg[g]]);
            o0[g] = (fvec4)(0.f); o1[g] = (fvec4)(0.f); o2[g] = (fvec4)(0.f);
        }

        #pragma unroll 2
        for (int k = 0; k < NUM_JOINTS; k++) {
            fvec4 w[4];
            #pragma unroll
            for (int g = 0; g < 4; g++)
                w[g] = __builtin_nontemporal_load(&Wb[(size_t)k * nf4 + qg[g]]);
            fvec4 r0 = Rl[k][0];  // {M00,M01,M02,M10}
            fvec4 r1 = Rl[k][1];  // {M11,M12,M20,M21}
            fvec4 r2 = Rl[k][2];  // {M22,pad,pad,pad}
            #pragma unroll
            for (int g = 0; g < 4; g++) {
                fvec4 t0 = fma4s(nx[g], r0.x, fma4s(ny[g], r0.y, mul4s(nz[g], r0.z)));
                fvec4 t1 = fma4s(nx[g], r0.w, fma4s(ny[g], r1.x, mul4s(nz[g], r1.y)));
                fvec4 t2 = fma4s(nx[g], r1.z, fma4s(ny[g], r1.w, mul4s(nz[g], r2.x)));
                o0[g] = fma4v(w[g], t0, o0[g]);
                o1[g] = fma4v(w[g], t1, o1[g]);
                o2[g] = fma4v(w[g], t2, o2[g]);
            }
        }

        #pragma unroll
        for (int g = 0; g < 4; g++) {
            __builtin_nontemporal_store(o0[g], &Ob[(size_t)0 * nf4 + qg[g]]);
            __builtin_nontemporal_store(o1[g], &Ob[(size_t)1 * nf4 + qg[g]]);
            __builtin_nontemporal_store(o2[g], &Ob[(size_t)2 * nf4 + qg[g]]);
        }
    } else if (q == n16) {
        // generic tail: vertices [16*n16, N) (not hit for N=100000: 16|100000/... 100000=16*6250)
        const float* Rf = (const float*)Rl;
        for (int n = n16 * 16; n < N; n++) {
            float vx = normals[(size_t)b * 3 * N + 0 * N + n];
            float vy = normals[(size_t)b * 3 * N + 1 * N + n];
            float vz = normals[(size_t)b * 3 * N + 2 * N + n];
            float s0 = 0.f, s1 = 0.f, s2 = 0.f;
            for (int k = 0; k < NUM_JOINTS; k++) {
                float w = weights[(size_t)b * NUM_JOINTS * N + (size_t)k * N + n];
                float t0 = Rf[k*12+0] * vx + Rf[k*12+1] * vy + Rf[k*12+2] * vz;
                float t1 = Rf[k*12+3] * vx + Rf[k*12+4] * vy + Rf[k*12+5] * vz;
                float t2 = Rf[k*12+6] * vx + Rf[k*12+7] * vy + Rf[k*12+8] * vz;
                s0 = fmaf(w, t0, s0); s1 = fmaf(w, t1, s1); s2 = fmaf(w, t2, s2);
            }
            out[(size_t)b * 3 * N + 0 * N + n] = s0;
            out[(size_t)b * 3 * N + 1 * N + n] = s1;
            out[(size_t)b * 3 * N + 2 * N + n] = s2;
        }
    }
}

extern "C" void kernel_launch(void* const* d_in, const int* in_sizes, int n_in,
                              void* d_out, int out_size, void* d_ws, size_t ws_size,
                              hipStream_t stream) {
    const float* normals = (const float*)d_in[0];  // (B,3,N)
    const float* pose = (const float*)d_in[1];     // (B,72)
    const float* weights = (const float*)d_in[2];  // (B,24,N)
    float* out = (float*)d_out;                    // (B,3,N)

    const int B = in_sizes[1] / 72;
    const int N = in_sizes[0] / (3 * B);

    const int n16 = (N >> 2) >> 2;                 // float4s per stream
    const int slots = n16 + 1;                     // +1 thread for generic tail
    const int gx = (slots + 255) / 256;
    skin_fused16_kernel<<<dim3(gx, B), dim3(256), 0, stream>>>(normals, pose, weights, out, N);
}